// Round 5
// baseline (11.692 us; speedup 1.0000x reference)
//
#include <hip/hip_runtime.h>
#include <math.h>

#define IEPS 1e-8f
#define BIGF 3.0e38f

typedef float f4 __attribute__((ext_vector_type(4)));

__device__ __forceinline__ float fast_rcp(float x) { return __builtin_amdgcn_rcpf(x); }

// Clip segment p + t*d, t in [0,1], against AABB [-hw,hw] x [-hh,hh].
// Returns clamp(t1 - t0, >=0): parameter length of the inside portion.
__device__ __forceinline__ float slab_dt(float px, float py, float dx, float dy,
                                         float hw, float hh)
{
    float rdx = fast_rcp(dx), rdy = fast_rcp(dy);
    float ax = (-hw - px) * rdx, bx = (hw - px) * rdx;
    float ay = (-hh - py) * rdy, by = (hh - py) * rdy;
    float txmin = fminf(ax, bx), txmax = fmaxf(ax, bx);
    float tymin = fminf(ay, by), tymax = fmaxf(ay, by);
    if (dx == 0.0f) { bool in = fabsf(px) <= hw; txmin = in ? -BIGF : BIGF; txmax = in ? BIGF : -BIGF; }
    if (dy == 0.0f) { bool in = fabsf(py) <= hh; tymin = in ? -BIGF : BIGF; tymax = in ? BIGF : -BIGF; }
    float t0 = fmaxf(fmaxf(txmin, tymin), 0.0f);   // v_max3
    float t1 = fminf(fminf(txmax, tymax), 1.0f);   // v_min3
    return fmaxf(t1 - t0, 0.0f);
}

// 256 threads/block, 256 boxes/block. 7 floats/box -> 1792 dwords = 448 f4 slots.
__global__ __launch_bounds__(256) void iou3d_partial_kernel(
    const float* __restrict__ pred,
    const float* __restrict__ target,
    const float* __restrict__ weight,
    float* __restrict__ partial,
    int N)
{
    __shared__ float sp[1792];
    __shared__ float st[1792];

    const int t   = threadIdx.x;
    const int bid = blockIdx.x;
    const int i   = bid * 256 + t;

    const int boxesHere = min(256, N - bid * 256);
    if (boxesHere == 256) {
        // fast path: fully-coalesced dwordx4 staging
        const f4* gp = (const f4*)(pred  + (size_t)bid * 1792);
        const f4* gt = (const f4*)(target + (size_t)bid * 1792);
        f4* lp = (f4*)sp;
        f4* lt = (f4*)st;
        lp[t] = gp[t];
        lt[t] = gt[t];
        if (t < 192) { lp[256 + t] = gp[256 + t]; lt[256 + t] = gt[256 + t]; }
    } else {
        // tail block (not hit for N = 262144): scalar staging
        int ndw = boxesHere * 7;
        for (int k = t; k < ndw; k += 256) {
            sp[k] = pred [(size_t)bid * 1792 + k];
            st[k] = target[(size_t)bid * 1792 + k];
        }
    }
    __syncthreads();

    float contrib = 0.0f;
    if (i < N) {
        float pb[7], tb[7];
        #pragma unroll
        for (int k = 0; k < 7; ++k) { pb[k] = sp[t * 7 + k]; tb[k] = st[t * 7 + k]; }

        float cx1 = pb[0], cy1 = pb[1], z1 = pb[2];
        float w1 = pb[3], h1 = pb[4], dz1 = pb[5], yaw1 = pb[6];
        float cx2 = tb[0], cy2 = tb[1], z2 = tb[2];
        float w2 = tb[3], h2 = tb[4], dz2 = tb[5], yaw2 = tb[6];

        float hw1 = 0.5f * w1, hh1 = 0.5f * h1;
        float hw2 = 0.5f * w2, hh2 = 0.5f * h2;
        float c1a = __cosf(yaw1), s1a = __sinf(yaw1);
        float c2a = __cosf(yaw2), s2a = __sinf(yaw2);

        // center offset rotated into each frame
        float dxg = cx2 - cx1, dyg = cy2 - cy1;
        float t12x =  dxg * c1a + dyg * s1a;     // box2 center in frame1
        float t12y = -dxg * s1a + dyg * c1a;
        float t21x = -(dxg * c2a + dyg * s2a);   // box1 center in frame2
        float t21y = -(-dxg * s2a + dyg * c2a);
        // relative rotation r = a2 - a1
        float cr = c2a * c1a + s2a * s1a;
        float sr = s2a * c1a - c2a * s1a;

        const float sgx[4] = {-1.0f, 1.0f, 1.0f, -1.0f};
        const float sgy[4] = {-1.0f, -1.0f, 1.0f, 1.0f};

        float q1x[4], q1y[4];  // box2 corners in frame1
        float p2x[4], p2y[4];  // box1 corners in frame2
        #pragma unroll
        for (int k = 0; k < 4; ++k) {
            float ux = sgx[k] * hw2, uy = sgy[k] * hh2;
            q1x[k] = t12x + ux * cr - uy * sr;   // R(+r)
            q1y[k] = t12y + ux * sr + uy * cr;
            float vx = sgx[k] * hw1, vy = sgy[k] * hh1;
            p2x[k] = t21x + vx * cr + vy * sr;   // R(-r)
            p2y[k] = t21y - vx * sr + vy * cr;
        }

        // Green's theorem over the intersection boundary, evaluated in frame2.
        float area2 = 0.0f;
        float sum_dt2 = 0.0f;
        #pragma unroll
        for (int k = 0; k < 4; ++k) {
            int k1 = (k + 1) & 3;
            float dx = p2x[k1] - p2x[k], dy = p2y[k1] - p2y[k];
            float dt = slab_dt(p2x[k], p2y[k], dx, dy, hw2, hh2);
            area2 += dt * (p2x[k] * dy - p2y[k] * dx);
            // box2's own edges: cross(p,d) == 2*hw2*hh2 constant in frame2
            float ex = q1x[k1] - q1x[k], ey = q1y[k1] - q1y[k];
            sum_dt2 += slab_dt(q1x[k], q1y[k], ex, ey, hw1, hh1);
        }
        area2 += 2.0f * hw2 * hh2 * sum_dt2;
        float inter2d = 0.5f * fabsf(area2);

        // z overlap
        float hz1 = 0.5f * dz1, hz2 = 0.5f * dz2;
        float zo = fmaxf(fminf(z1 + hz1, z2 + hz2) - fmaxf(z1 - hz1, z2 - hz2), 0.0f);

        float inter3d = inter2d * zo;
        float v1 = w1 * h1 * dz1;
        float v2 = w2 * h2 * dz2;
        float denom = fmaxf(v1 + v2 - inter3d, IEPS);
        float iou = inter3d / denom;

        contrib = weight[i] * (1.0f - iou);
    }

    // wave(64) reduction
    #pragma unroll
    for (int off = 32; off > 0; off >>= 1)
        contrib += __shfl_down(contrib, off);

    __shared__ float sred[4];
    int lane = t & 63;
    int wid  = t >> 6;
    if (lane == 0) sred[wid] = contrib;
    __syncthreads();
    if (t == 0)
        partial[bid] = sred[0] + sred[1] + sred[2] + sred[3];
}

__global__ __launch_bounds__(256) void iou3d_reduce_kernel(
    const float* __restrict__ partial, float* __restrict__ out,
    int nPart, float invN)
{
    int t = threadIdx.x;
    float s = 0.0f;
    for (int k = t; k < nPart; k += 256) s += partial[k];

    #pragma unroll
    for (int off = 32; off > 0; off >>= 1)
        s += __shfl_down(s, off);

    __shared__ float sm[4];
    if ((t & 63) == 0) sm[t >> 6] = s;
    __syncthreads();
    if (t == 0)
        out[0] = (sm[0] + sm[1] + sm[2] + sm[3]) * invN;
}

extern "C" void kernel_launch(void* const* d_in, const int* in_sizes, int n_in,
                              void* d_out, int out_size, void* d_ws, size_t ws_size,
                              hipStream_t stream) {
    const float* pred   = (const float*)d_in[0];
    const float* target = (const float*)d_in[1];
    const float* weight = (const float*)d_in[2];
    float* out = (float*)d_out;
    float* partial = (float*)d_ws;

    int N = in_sizes[0] / 7;
    float invN = 1.0f / (float)N;

    int block = 256;
    int grid = (N + block - 1) / block;   // 1024 for N=262144
    iou3d_partial_kernel<<<grid, block, 0, stream>>>(pred, target, weight, partial, N);
    iou3d_reduce_kernel<<<1, 256, 0, stream>>>(partial, out, grid, invN);
}